// Round 4
// baseline (20.323 us; speedup 1.0000x reference)
//
#include <hip/hip_runtime.h>
#include <math.h>

// BlockwiseQuantizationOptim: 1024x1024 f32, 64 blocks of 128x128, L=256, T=100.
// Closed-form softmax over uniform levels: e_l = r^{|p-l|}, r = exp(-100/255).
//   S  = rf*A[k] + r1f*A[j],  j = 254-k
//   W  = rf*(k*A[k]-B[k]) + r1f*((k+1)*A[j]+B[j])
// A[k]=sum_{m<=k} r^m, B[k]=sum m r^m; folded float4 table:
//   tab4[k] = (A[k], k*A[k]-B[k], A[j], (k+1)*A[j]+B[j])
// bin_mass: ONE ds_add_u64 per element packs down-seed (level k) and up-seed
// (level k+1) as 2^23 fixed point (per-bin sums < 2^30, no cross-carry).
// Geometric scans per column reconstruct the histogram; entropy partial is
// atomically added to the output (no second kernel).
//
// LDS layout: idx(c,l) = (l&15)*273 + c*17 + (l>>4); per-column PARITY SWAP
// of lo/hi halves so half-word scan reads hit both bank parities.

#define NT 512
#define LVL 256
#define FXS 8388608.0f            // 2^23
#define INV_FXS (1.0f / 8388608.0f)
#define DEPIDX(c, l) ((((l) & 15) * 273) + ((c) * 17) + ((l) >> 4))
#define NDEP 4368                 // > max idx 4365

__global__ __launch_bounds__(NT)
void bq_main(const float* __restrict__ Wt,
             const float* __restrict__ wmin_in,
             const float* __restrict__ wmax_in,
             float* __restrict__ dq_out,
             float* __restrict__ ent_out)
{
    __shared__ float4 tab4[LVL];
    __shared__ unsigned long long dep[NDEP];
    __shared__ float wred[8];

    const int tid = threadIdx.x;
    const int wg  = blockIdx.x;
    const int n = wg >> 3, slab = wg & 7;   // block 0..63, 16-col slab 0..7

    const float LN2 = 0.69314718055994531f;
    const float L2R = -(100.0f / 255.0f) * 1.4426950408889634f;  // log2(r)
    const float r = __builtin_amdgcn_exp2f(L2R);
    const float inv1mr = 1.0f / (1.0f - r);

    if (tid < LVL) {
        const int k = tid;
        const float rk1 = __builtin_amdgcn_exp2f(L2R * (float)(k + 1));
        const float Ak = (1.0f - rk1) * inv1mr;
        const float Bk = (r - (float)(k + 1) * rk1 + (float)k * rk1 * r)
                         * (inv1mr * inv1mr);
        const float rj1 = __builtin_amdgcn_exp2f(L2R * (float)(255 - k));
        const float Aj = (1.0f - rj1) * inv1mr;
        const float Bj = (r - (float)(255 - k) * rj1 + (float)(254 - k) * rj1 * r)
                         * (inv1mr * inv1mr);
        tab4[k] = make_float4(Ak, (float)k * Ak - Bk,
                              Aj, (float)(k + 1) * Aj + Bj);
    }
    for (int q = tid; q < NDEP; q += NT) dep[q] = 0ull;

    const float bmn = wmin_in[n], bmx = wmax_in[n];
    const float wmn = fminf(bmn, bmx - 1e-6f);
    const float wmx = fmaxf(bmx, wmn + 1e-6f);
    const float scale = wmx - wmn;
    const float invsc = 255.0f / (scale + 1e-6f);
    const float sc255 = scale * (1.0f / 255.0f);

    __syncthreads();

    // ---- phase 1: closed-form softmax + dequant + 1 packed u64 deposit/elem
    {
        const int row = tid >> 2;              // 0..127
        const int c0  = (tid & 3) * 4;         // 0,4,8,12
        const int R = (n >> 3) * 128 + row;
        const int C = (n & 7) * 128 + slab * 16 + c0;
        const float4 x4 = *reinterpret_cast<const float4*>(Wt + (size_t)R * 1024 + C);
        float xs[4] = {x4.x, x4.y, x4.z, x4.w};
        float dq[4];
        #pragma unroll
        for (int u = 0; u < 4; ++u) {
            const float p = (xs[u] - wmn) * invsc;   // in [0,255)
            int k = (int)p; k = (k > 254) ? 254 : k;
            const float f   = p - (float)k;
            const float rf  = __builtin_amdgcn_exp2f(L2R * f);
            const float r1f = __builtin_amdgcn_exp2f(L2R * (1.0f - f));
            const float4 t = tab4[k];
            const float S  = rf * t.x + r1f * t.z;
            const float Wn = rf * t.y + r1f * t.w;
            const float invS = __builtin_amdgcn_rcpf(S);
            dq[u] = Wn * invS * sc255 + wmn;
            const int c = c0 + u;
            const unsigned dn = (unsigned)(rf  * invS * FXS + 0.5f);
            const unsigned up = (unsigned)(r1f * invS * FXS + 0.5f);
            // parity swap: even c -> (hi=up, lo=dn); odd c -> (hi=dn, lo=up)
            const unsigned long long val = (c & 1)
                ? (((unsigned long long)dn << 32) | up)
                : (((unsigned long long)up << 32) | dn);
            atomicAdd(&dep[DEPIDX(c, k)], val);
        }
        float4 o4; o4.x = dq[0]; o4.y = dq[1]; o4.z = dq[2]; o4.w = dq[3];
        *reinterpret_cast<float4*>(dq_out + (size_t)R * 1024 + C) = o4;
    }
    __syncthreads();

    // ---- phase 2: geometric scans; thread = (dir, col, chunk of 16 levels)
    // dir0 owns the (c&1) half-words (down-chain), dir1 the opposite halves
    // (up-chain). Byte-disjoint -> no cross-wave races; same-col chunk
    // neighbors are lanes of the same wave (lockstep read-before-write).
    {
        unsigned* a32 = reinterpret_cast<unsigned*>(&dep[0]);
        float*    f32v = reinterpret_cast<float*>(&dep[0]);
        const int ch  = tid & 15;              // chunk: levels [16ch, 16ch+15]
        const int col = (tid >> 4) & 15;
        const int dir = tid >> 8;              // 0: down (hi->lo), 1: up
        const int half = (col & 1) ^ dir;      // which u32 half this dir uses
        float lv[16];
        float v = 0.0f;
        if (dir == 0) {
            #pragma unroll
            for (int i = 15; i >= 0; --i) {
                const int l = ch * 16 + i;
                v = v * r + (float)a32[2 * DEPIDX(col, l) + half] * INV_FXS;
                lv[i] = v;
            }
        } else {
            #pragma unroll
            for (int i = 0; i < 16; ++i) {
                const int l = ch * 16 + i;
                float seed = 0.0f;
                if (i > 0) {
                    seed = (float)a32[2 * DEPIDX(col, l - 1) + half] * INV_FXS;
                } else if (ch > 0) {
                    seed = (float)a32[2 * DEPIDX(col, l - 1) + half] * INV_FXS;
                }
                v = v * r + seed;
                lv[i] = v;
            }
        }
        // cross-chunk carry: weighted Hillis-Steele over 16 chunks, in-wave
        const float r16 = __builtin_amdgcn_exp2f(L2R * 16.0f);
        float u = v, rp = r16;
        #pragma unroll
        for (int s = 1; s <= 8; s <<= 1) {
            const float o = (dir == 0) ? __shfl_down(u, s, 16) : __shfl_up(u, s, 16);
            const bool ok = (dir == 0) ? (ch + s < 16) : (ch >= s);
            u += ok ? rp * o : 0.0f;
            rp *= rp;
        }
        float cv;
        if (dir == 0) cv = (ch < 15) ? __shfl_down(u, 1, 16) : 0.0f;
        else          cv = (ch > 0)  ? __shfl_up(u, 1, 16)  : 0.0f;
        float m = cv * r;
        if (dir == 0) {
            #pragma unroll
            for (int i = 15; i >= 0; --i) {
                const int l = ch * 16 + i;
                f32v[2 * DEPIDX(col, l) + half] = lv[i] + m; m *= r;
            }
        } else {
            #pragma unroll
            for (int i = 0; i < 16; ++i) {
                const int l = ch * 16 + i;
                f32v[2 * DEPIDX(col, l) + half] = lv[i] + m; m *= r;
            }
        }
    }
    __syncthreads();

    // ---- phase 3: entropy over this slab's 16x256 bins (halves sum -> order
    // of lo/hi is irrelevant)
    float hsum = 0.0f;
    #pragma unroll
    for (int t = 0; t < 8; ++t) {
        const int q = tid + t * NT;
        const int c = q & 15, l = q >> 4;
        const unsigned long long w = dep[DEPIDX(c, l)];
        const float D = __uint_as_float((unsigned)w);
        const float U = __uint_as_float((unsigned)(w >> 32));
        const float ph = (D + U) * (1.0f / 16384.0f);
        hsum -= ph * (__builtin_amdgcn_logf(ph + 1e-6f) * LN2);
    }
    #pragma unroll
    for (int off = 32; off > 0; off >>= 1) hsum += __shfl_down(hsum, off);
    if ((tid & 63) == 0) wred[tid >> 6] = hsum;
    __syncthreads();
    if (tid == 0) {
        float tot = 0.0f;
        #pragma unroll
        for (int w = 0; w < 8; ++w) tot += wred[w];
        atomicAdd(ent_out, tot);
    }
}

extern "C" void kernel_launch(void* const* d_in, const int* in_sizes, int n_in,
                              void* d_out, int out_size, void* d_ws, size_t ws_size,
                              hipStream_t stream)
{
    const float* Wt  = (const float*)d_in[0];
    const float* wmn = (const float*)d_in[1];
    const float* wmx = (const float*)d_in[2];
    float* out = (float*)d_out;   // [1048576 dequant] + [1 entropy]

    hipMemsetAsync(out + 1048576, 0, sizeof(float), stream);
    bq_main<<<512, NT, 0, stream>>>(Wt, wmn, wmx, out, out + 1048576);
}